// Round 12
// baseline (222.173 us; speedup 1.0000x reference)
//
#include <hip/hip_runtime.h>

// ============================================================================
// ContDecoder on MI355X — bf16 MFMA, round 14: in-place activations ->
// MPTS=64 AT 2 blocks/CU (the untested corner: reuse x2 + ILP x4 + dual
// barrier domains simultaneously).
// 1024 threads (16 waves), 78.8 KB dynamic LDS, 2 blocks/CU (159.7/160 KB).
//
// r13's asm counted-wait rings were null -> per-wave load latency falsified.
// Config matrix: r3 (MPTS=64, 1 blk/CU) 156; r8 (MPTS=32, 2 blk/CU) 145.
// reuse+occupancy together needed SROW small enough for 64-pt rows at 2
// blocks: achieved by IN-PLACE layer writes (read-all -> barrier -> write
// over input) in one 544-elem H region: row = [xin 0..64 | H 64..608 | 616).
//   - weight traffic per CU halves (each frag feeds 64 points, 4 MFMAs)
//   - stale k-ranges [kact,khp) already zero-masked by the pack; L1's tail
//     [580,608) = L0 pad neurons (exact 0) + prologue-zeroed pad
//   - L1..L6 have NT<=16 -> each wave owns <=1 unit -> one mid-layer
//     barrier makes in-place safe; L0 reads only xin (disjoint, no barrier)
//   - SROW=616: 1232B stride == 20 mod 32 banks — same class as 872 ->
//     identical bank behavior
// Kept from r8 (best): 16x16x32, swapped mfma(W,X)->D[n,pt], ds_write_b64
// epilogue + float4 bias. All asm/SGB machinery dropped (null r8/r12/r13).
// ============================================================================

#define NTH     1024
#define NWAVES  16
#define MPTS    64              // points per block (4 m-tiles of 16)
#define MTILES  (MPTS / 16)
#define SROW    616             // LDS row stride in bf16 elems (1232 B)
#define XIN_OFF 0
#define HSEG    64              // H region: [64, 608)
#define NPOINTS (8 * 16384)
#define GRIDX   (NPOINTS / MPTS)   // 2048 blocks
#define LDSBYTES (MPTS * SROW * 2) // 78848 -> 2 blocks/CU (+1KB static)

typedef short          short8  __attribute__((ext_vector_type(8)));
typedef short          short4v __attribute__((ext_vector_type(4)));
typedef float          f32x4   __attribute__((ext_vector_type(4)));
typedef unsigned short u16;

__device__ __forceinline__ u16 f2bf(float f) {
    unsigned int u = __builtin_bit_cast(unsigned int, f);
    u += 0x7fffu + ((u >> 16) & 1u);        // round-to-nearest-even
    return (u16)(u >> 16);
}

// ---------------------------------------------------------------------------
// Packed-weight geometry (16B fragments of 8 bf16). frag (l, nt, s, lane)
// holds B[s*32 + (lane>>4)*8 + j][nt*16 + (lane&15)], j=0..7, zero-padded
// outside (kact, nact) — the zero k-rows are what mask stale in-place data.
// Identical pack as r4..r13 (HW-verified swapped-operand layout).
//   l : KHpad KSteps Ntiles  frag_base
//   0 :    0    2     33        0
//   1 :  544   19     16     4224
//   2 :  256   10      8    23680
//   3 :  128    6      4    28800
//   4 :   64    4      2    30336
//   5 :   32    3      1    30848
//   6 :   32    1      1    31040   total 31104 frags = 497664 B in d_ws
// ---------------------------------------------------------------------------
__constant__ int pk_base8[8] = {0, 4224, 23680, 28800, 30336, 30848, 31040, 31104};
__constant__ int pk_ks[7]    = {2, 19, 10, 6, 4, 3, 1};
__constant__ int pk_khp[7]   = {0, 544, 256, 128, 64, 32, 32};
__constant__ int pk_kact[7]  = {0, 516, 256, 128, 64, 32, 16};
__constant__ int pk_nact[7]  = {516, 256, 128, 64, 32, 16, 2};

struct WPtrs { const float* W[7]; };

__global__ void pack_weights(WPtrs wp, u16* __restrict__ out)
{
    const int f = blockIdx.x * blockDim.x + threadIdx.x;
    if (f >= 31104) return;
    int l = 0;
    while (l < 6 && f >= pk_base8[l + 1]) ++l;
    const int r    = f - pk_base8[l];
    const int lane = r & 63;
    const int t    = r >> 6;
    const int ks   = pk_ks[l];
    const int s    = t % ks;
    const int nt   = t / ks;
    const int n    = nt * 16 + (lane & 15);
    const int k0   = s * 32 + (lane >> 4) * 8;
    const int nact = pk_nact[l];
    const int khp  = pk_khp[l];
    const int kact = pk_kact[l];
    const float* W = wp.W[l];

    union { short8 v; u16 e[8]; } frag;
#pragma unroll
    for (int j = 0; j < 8; ++j) {
        const int k = k0 + j;
        float v = 0.0f;
        if (n < nact) {
            if (k < khp) {
                if (k < kact) v = W[k * nact + n];
            } else {
                const int xr = k - khp;
                if (xr < 37) v = W[(kact + xr) * nact + n];
            }
        }
        frag.e[j] = f2bf(v);
    }
    *(short8*)(out + (size_t)f * 8) = frag.v;
}

// ---------------------------------------------------------------------------
// Layer compute core: one unit (n-tile nt) across all 4 m-tiles.
// Per K-step: 4 ds_read_b128 (A, one per m-tile) + 1 global load (B, each
// frag read ONCE per 64 points) + 4 MFMA (swapped: D[n,pt]).
// D: col pt = lane&15, row n = (lane>>4)*4 + r.
// ---------------------------------------------------------------------------
template<int KHP, bool XIN, int MS>
__device__ __forceinline__ void unit_compute(const u16* __restrict__ bp,
                                             const u16* const* arow,
                                             f32x4* acc)
{
    constexpr int KHS = KHP / 32;
    constexpr int KS  = KHS + (XIN ? 2 : 0);
#pragma unroll
    for (int s = 0; s < KS; ++s) {
        const int ab = (s < KHS) ? (HSEG + s * 32)
                                 : (XIN_OFF + (s - KHS) * 32);
        short8 a[MS];
#pragma unroll
        for (int m = 0; m < MS; ++m)
            a[m] = *(const short8*)(arow[m] + ab);
        const short8 b = *(const short8*)(bp + (size_t)s * 512);
#pragma unroll
        for (int m = 0; m < MS; ++m)
            acc[m] = __builtin_amdgcn_mfma_f32_16x16x32_bf16(b, a[m], acc[m], 0, 0, 0);
    }
}

template<int NACT, bool RELU, int MS>
__device__ __forceinline__ void unit_store_lds(const f32x4* acc,
                                               const float* __restrict__ bias,
                                               u16* __restrict__ s_act,
                                               int nt, int lm, int lq)
{
    const int bn = nt * 16 + lq * 4;
    float bv[4];
    if (bn + 4 <= NACT) {
        const f32x4 b4 = *(const f32x4*)(bias + bn);
        bv[0] = b4[0]; bv[1] = b4[1]; bv[2] = b4[2]; bv[3] = b4[3];
    } else {
#pragma unroll
        for (int r = 0; r < 4; ++r)
            bv[r] = (bn + r < NACT) ? bias[bn + r] : 0.f;
    }
#pragma unroll
    for (int m = 0; m < MS; ++m) {
        short4v o;
#pragma unroll
        for (int r = 0; r < 4; ++r) {
            float v = acc[m][r] + bv[r];
            if (RELU) v = fmaxf(v, 0.f);
            o[r] = (short)f2bf(v);
        }
        *(short4v*)(s_act + (size_t)(m * 16 + lm) * SROW + HSEG + bn) = o;
    }
}

struct MainParams {
    const float* lr;     // [B,2,64,64]
    const float* ctx;    // [B,32,64,64]
    const float* eps;    // [B,64,64]
    const float* coord;  // [B,N,2]
    const float* Bb[7];  // biases (fp32)
    const u16*   wpack;  // packed bf16 weights in d_ws
    float*       out;    // [B,N,2]
};

// In-place hidden layer (L1..L5): NT<=16, each wave owns <=1 unit.
// compute (reads H+xin) -> barrier -> write H (over the input region).
template<int KHP, int NT, int NACT, int LBASE>
__device__ __forceinline__ void mlayer_ip(const u16* __restrict__ wpack,
                                          const float* __restrict__ bias,
                                          u16* __restrict__ s_act,
                                          const u16* const* arow,
                                          int wave, int lane)
{
    constexpr int MS = MTILES;
    const int lm = lane & 15;
    const int lq = lane >> 4;
    f32x4 acc[MS];
#pragma unroll
    for (int m = 0; m < MS; ++m) acc[m] = (f32x4){0.f, 0.f, 0.f, 0.f};

    const bool active = (wave < NT);
    if (active) {
        const u16* bp = wpack + LBASE + lane * 8 + (size_t)wave * (KHP / 32 + 2) * 512;
        unit_compute<KHP, true, MS>(bp, arow, acc);
    }
    __syncthreads();                       // all reads done before overwrite
    if (active)
        unit_store_lds<NACT, true, MS>(acc, bias, s_act, wave, lm, lq);
}

__global__ __launch_bounds__(NTH, 8)   // 8 waves/EU = 32 waves/CU = 2 blocks
void cont_decoder_mfma(MainParams p)
{
    extern __shared__ u16 s_act[];         // MPTS*SROW bf16 = 78848 B
    __shared__ int   s_x0[MPTS], s_y0[MPTS];
    __shared__ float s_wx[MPTS], s_wy[MPTS];

    const int tid  = threadIdx.x;
    const int wave = tid >> 6;
    const int lane = tid & 63;
    const int lm   = lane & 15;
    const int lq   = lane >> 4;
    const int p0   = blockIdx.x * MPTS;
    const int b    = p0 >> 14;             // 16384 points per batch

    // ---- zero pad regions: xin[37..64) and H tail [592..608) ----
    for (int i = tid; i < MPTS * 43; i += NTH) {
        const int pt = i / 43, c = i % 43;
        const int col = (c < 27) ? (37 + c) : (592 + (c - 27));
        s_act[pt * SROW + col] = 0;
    }

    // ---- bilinear params + coord features ----
    if (tid < MPTS) {
        const int pt = p0 + tid;
        const float cx = p.coord[2 * pt];
        const float cy = p.coord[2 * pt + 1];
        const float gx = (cx + 1.0f) * 32.0f - 0.5f;   // align_corners=False
        const float gy = (cy + 1.0f) * 32.0f - 0.5f;
        const float fx0 = floorf(gx), fy0 = floorf(gy);
        s_x0[tid] = (int)fx0;
        s_y0[tid] = (int)fy0;
        s_wx[tid] = gx - fx0;
        s_wy[tid] = gy - fy0;
        s_act[tid * SROW + 32] = f2bf(cx);
        s_act[tid * SROW + 33] = f2bf(cy);
    }
    __syncthreads();

    // ---- sample 35 channels/point (ref swaps spatial axes: val = g[b,c,x,y]) ----
    for (int idx = tid; idx < MPTS * 35; idx += NTH) {
        const int t = idx / 35;
        const int c = idx % 35;
        const float* base;
        int col;
        if (c < 32)      { base = p.ctx + (size_t)(b * 32 + c) * 4096;       col = c; }
        else if (c < 34) { base = p.lr  + (size_t)(b * 2 + (c - 32)) * 4096; col = 34 + (c - 32); }
        else             { base = p.eps + (size_t)b * 4096;                   col = 36; }

        const int   x0 = s_x0[t], y0 = s_y0[t];
        const float wx = s_wx[t], wy = s_wy[t];
        const int x1 = x0 + 1, y1 = y0 + 1;
        const bool xv0 = (x0 >= 0) & (x0 < 64);
        const bool xv1 = (x1 >= 0) & (x1 < 64);
        const bool yv0 = (y0 >= 0) & (y0 < 64);
        const bool yv1 = (y1 >= 0) & (y1 < 64);
        const int xc0 = min(max(x0, 0), 63), xc1 = min(max(x1, 0), 63);
        const int yc0 = min(max(y0, 0), 63), yc1 = min(max(y1, 0), 63);

        const float w00 = (1.0f - wx) * (1.0f - wy) * ((xv0 && yv0) ? 1.0f : 0.0f);
        const float w10 = wx * (1.0f - wy)          * ((xv1 && yv0) ? 1.0f : 0.0f);
        const float w01 = (1.0f - wx) * wy          * ((xv0 && yv1) ? 1.0f : 0.0f);
        const float w11 = wx * wy                   * ((xv1 && yv1) ? 1.0f : 0.0f);

        const float val = w00 * base[xc0 * 64 + yc0]
                        + w10 * base[xc1 * 64 + yc0]
                        + w01 * base[xc0 * 64 + yc1]
                        + w11 * base[xc1 * 64 + yc1];
        s_act[t * SROW + col] = f2bf(val);
    }
    __syncthreads();

    // ---- per-wave A-row base pointers (4 m-tiles) ----
    const u16* arow[MTILES];
#pragma unroll
    for (int m = 0; m < MTILES; ++m)
        arow[m] = s_act + (m * 16 + lm) * SROW + lq * 8;

    // ---- L0: reads xin only, writes H [64,592) — disjoint, r8-style loop ----
    {
        for (int nt = wave; nt < 33; nt += NWAVES) {
            f32x4 acc[MTILES];
#pragma unroll
            for (int m = 0; m < MTILES; ++m) acc[m] = (f32x4){0.f, 0.f, 0.f, 0.f};
            const u16* bp = p.wpack + 0 + lane * 8 + (size_t)nt * 2 * 512;
            unit_compute<0, true, MTILES>(bp, arow, acc);
            unit_store_lds<516, true, MTILES>(acc, p.Bb[0], s_act, nt, lm, lq);
        }
    }
    __syncthreads();

    // ---- L1..L5: in-place (compute -> barrier -> overwrite input) ----
    //          KHP  NT NACT LBASE
    mlayer_ip<544, 16, 256, 33792 >(p.wpack, p.Bb[1], s_act, arow, wave, lane);
    __syncthreads();
    mlayer_ip<256,  8, 128, 189440>(p.wpack, p.Bb[2], s_act, arow, wave, lane);
    __syncthreads();
    mlayer_ip<128,  4,  64, 230400>(p.wpack, p.Bb[3], s_act, arow, wave, lane);
    __syncthreads();
    mlayer_ip< 64,  2,  32, 242688>(p.wpack, p.Bb[4], s_act, arow, wave, lane);
    __syncthreads();
    mlayer_ip< 32,  1,  16, 246784>(p.wpack, p.Bb[5], s_act, arow, wave, lane);
    __syncthreads();

    // ---- L6: reads H [64,96) (k 16..31 zero-masked by pack), global out ----
    if (wave == 0) {
        f32x4 acc[MTILES];
#pragma unroll
        for (int m = 0; m < MTILES; ++m) acc[m] = (f32x4){0.f, 0.f, 0.f, 0.f};
        const u16* bp = p.wpack + 248320 + lane * 8;
        unit_compute<32, false, MTILES>(bp, arow, acc);
        if (lq == 0) {
            const float b0 = p.Bb[6][0], b1 = p.Bb[6][1];
#pragma unroll
            for (int m = 0; m < MTILES; ++m) {
                float2 o;
                o.x = acc[m][0] + b0;
                o.y = acc[m][1] + b1;
                *(float2*)(p.out + (size_t)(p0 + m * 16 + lm) * 2) = o;
            }
        }
    }
}

extern "C" void kernel_launch(void* const* d_in, const int* in_sizes, int n_in,
                              void* d_out, int out_size, void* d_ws, size_t ws_size,
                              hipStream_t stream)
{
    WPtrs wp;
    for (int l = 0; l < 7; ++l) wp.W[l] = (const float*)d_in[4 + 2 * l];

    MainParams p;
    p.lr    = (const float*)d_in[0];
    p.ctx   = (const float*)d_in[1];
    p.eps   = (const float*)d_in[2];
    p.coord = (const float*)d_in[3];
    for (int l = 0; l < 7; ++l) p.Bb[l] = (const float*)d_in[5 + 2 * l];
    p.wpack = (const u16*)d_ws;
    p.out   = (float*)d_out;

    // Opt in to large dynamic LDS (idempotent; not a stream op, capture-safe).
    hipFuncSetAttribute((const void*)cont_decoder_mfma,
                        hipFuncAttributeMaxDynamicSharedMemorySize, LDSBYTES);

    hipLaunchKernelGGL(pack_weights, dim3(122), dim3(256), 0, stream, wp, (u16*)d_ws);
    hipLaunchKernelGGL(cont_decoder_mfma, dim3(GRIDX), dim3(NTH), LDSBYTES, stream, p);
}

// Round 13
// 211.158 us; speedup vs baseline: 1.0522x; 1.0522x over previous
//
#include <hip/hip_runtime.h>

// ============================================================================
// ContDecoder on MI355X — bf16 MFMA, round 15: 2m x 2n pair-waves on the
// in-place MPTS=64 layout — cuts LDS A-read traffic 42%/point at FULL
// 16-wave parallelism (the mapping that escapes the traffic/parallelism
// vice that bound r6/r7/r9/r10/r14).
// 1024 threads (16 waves), 78.8 KB dynamic LDS, 2 blocks/CU.
//
// LDS-port ledger (reconciles all 14 rounds): ds_read_b128 ~12cyc -> r8
// spends ~187K + 70K conflict of 350K CU-cycles on the LDS port; every
// prior traffic cut paid with parallelism. Here wave (mg,ng) owns m-tiles
// {2mg,2mg+1} and n-tiles {ng(+8)}: per K-step 2 A-reads feed 4 MFMAs
// (A shared across n-pair, W shared across m-pair; sibling mg-wave L1-hits
// the same W frags). Per-block A-reads 1812->1136; tail parallelism 2x r14
// (L2: 16 waves, L5/L6: 2).
// Kept verified pieces: r14 in-place row [xin 0..64 | H 64..608 | 616)
// (stale k-ranges zero-masked by pack), swapped mfma(W,X)->D[n,pt],
// ds_write_b64 epilogue + float4 bias, 16x16x32 pack (r4..r14).
// ============================================================================

#define NTH     1024
#define NWAVES  16
#define MPTS    64              // points per block (4 m-tiles of 16)
#define MTILES  (MPTS / 16)
#define SROW    616             // LDS row stride in bf16 elems (1232 B)
#define XIN_OFF 0
#define HSEG    64              // H region: [64, 608)
#define NPOINTS (8 * 16384)
#define GRIDX   (NPOINTS / MPTS)   // 2048 blocks
#define LDSBYTES (MPTS * SROW * 2) // 78848 -> 2 blocks/CU

typedef short          short8  __attribute__((ext_vector_type(8)));
typedef short          short4v __attribute__((ext_vector_type(4)));
typedef float          f32x4   __attribute__((ext_vector_type(4)));
typedef unsigned short u16;

__device__ __forceinline__ u16 f2bf(float f) {
    unsigned int u = __builtin_bit_cast(unsigned int, f);
    u += 0x7fffu + ((u >> 16) & 1u);        // round-to-nearest-even
    return (u16)(u >> 16);
}

// ---------------------------------------------------------------------------
// Packed-weight geometry (16B fragments of 8 bf16). frag (l, nt, s, lane)
// holds B[s*32 + (lane>>4)*8 + j][nt*16 + (lane&15)], j=0..7, zero-padded
// outside (kact, nact) — zero k-rows mask stale in-place data.
// Identical pack as r4..r14 (HW-verified swapped-operand layout).
//   l : KHpad KSteps Ntiles  frag_base
//   0 :    0    2     33        0
//   1 :  544   19     16     4224
//   2 :  256   10      8    23680
//   3 :  128    6      4    28800
//   4 :   64    4      2    30336
//   5 :   32    3      1    30848
//   6 :   32    1      1    31040   total 31104 frags = 497664 B in d_ws
// ---------------------------------------------------------------------------
__constant__ int pk_base8[8] = {0, 4224, 23680, 28800, 30336, 30848, 31040, 31104};
__constant__ int pk_ks[7]    = {2, 19, 10, 6, 4, 3, 1};
__constant__ int pk_khp[7]   = {0, 544, 256, 128, 64, 32, 32};
__constant__ int pk_kact[7]  = {0, 516, 256, 128, 64, 32, 16};
__constant__ int pk_nact[7]  = {516, 256, 128, 64, 32, 16, 2};

struct WPtrs { const float* W[7]; };

__global__ void pack_weights(WPtrs wp, u16* __restrict__ out)
{
    const int f = blockIdx.x * blockDim.x + threadIdx.x;
    if (f >= 31104) return;
    int l = 0;
    while (l < 6 && f >= pk_base8[l + 1]) ++l;
    const int r    = f - pk_base8[l];
    const int lane = r & 63;
    const int t    = r >> 6;
    const int ks   = pk_ks[l];
    const int s    = t % ks;
    const int nt   = t / ks;
    const int n    = nt * 16 + (lane & 15);
    const int k0   = s * 32 + (lane >> 4) * 8;
    const int nact = pk_nact[l];
    const int khp  = pk_khp[l];
    const int kact = pk_kact[l];
    const float* W = wp.W[l];

    union { short8 v; u16 e[8]; } frag;
#pragma unroll
    for (int j = 0; j < 8; ++j) {
        const int k = k0 + j;
        float v = 0.0f;
        if (n < nact) {
            if (k < khp) {
                if (k < kact) v = W[k * nact + n];
            } else {
                const int xr = k - khp;
                if (xr < 37) v = W[(kact + xr) * nact + n];
            }
        }
        frag.e[j] = f2bf(v);
    }
    *(short8*)(out + (size_t)f * 8) = frag.v;
}

struct MainParams {
    const float* lr;     // [B,2,64,64]
    const float* ctx;    // [B,32,64,64]
    const float* eps;    // [B,64,64]
    const float* coord;  // [B,N,2]
    const float* Bb[7];  // biases (fp32)
    const u16*   wpack;  // packed bf16 weights in d_ws
    float*       out;    // [B,N,2]
};

// ---------------------------------------------------------------------------
// Pair-store: one n-tile's outputs for the wave's 2 m-tiles.
// D (swapped operands): col pt = lane&15, row n = (lane>>4)*4 + r.
// ---------------------------------------------------------------------------
template<int NACT, bool RELU>
__device__ __forceinline__ void store_nt(const f32x4* accm,   // [2] m-pair
                                         const float* __restrict__ bias,
                                         u16* __restrict__ s_act,
                                         int nt, int mbase, int lm, int lq)
{
    const int bn = nt * 16 + lq * 4;
    float bv[4];
    if (bn + 4 <= NACT) {
        const f32x4 b4 = *(const f32x4*)(bias + bn);
        bv[0] = b4[0]; bv[1] = b4[1]; bv[2] = b4[2]; bv[3] = b4[3];
    } else {
#pragma unroll
        for (int r = 0; r < 4; ++r)
            bv[r] = (bn + r < NACT) ? bias[bn + r] : 0.f;
    }
#pragma unroll
    for (int m = 0; m < 2; ++m) {
        short4v o;
#pragma unroll
        for (int r = 0; r < 4; ++r) {
            float v = accm[m][r] + bv[r];
            if (RELU) v = fmaxf(v, 0.f);
            o[r] = (short)f2bf(v);
        }
        *(short4v*)(s_act + (size_t)((mbase + m) * 16 + lm) * SROW + HSEG + bn) = o;
    }
}

// ---------------------------------------------------------------------------
// One MLP layer, (mg, ng) pair-wave mapping. mg = wave&1 owns m-tiles
// {2mg, 2mg+1}; ng = wave>>1 owns n-tiles {ng, ng+8, ng+16, ...} < NT,
// processed as pairs {ng+16g, ng+8+16g}. Per K-step: 2 ds_read (A, shared
// across the n-pair) + <=2 global loads (W, shared across the m-pair via
// sibling wave's L1 residency) + <=4 MFMA (swapped: D[n,pt]).
// IPBAR: in-place layer — compute all, barrier, then overwrite input.
// ---------------------------------------------------------------------------
template<int KHP, int NT, int NACT, int LBASE,
         bool XIN, bool RELU, bool GOUT, bool IPBAR>
__device__ __forceinline__ void mlayer(const u16* __restrict__ wpack,
                                       const float* __restrict__ bias,
                                       u16* __restrict__ s_act,
                                       float* __restrict__ gout, int p0,
                                       int wave, int lane)
{
    constexpr int KHS = KHP / 32;
    constexpr int KS  = KHS + (XIN ? 2 : 0);
    const int lm = lane & 15;
    const int lq = lane >> 4;
    const int mg = wave & 1;
    const int ng = wave >> 1;          // 0..7
    const int mbase = mg * 2;          // m-tiles {mbase, mbase+1}

    const u16* arow0 = s_act + (size_t)((mbase * 16) + lm) * SROW + lq * 8;
    const u16* arow1 = arow0 + (size_t)16 * SROW;
    const u16* wl = wpack + LBASE + lane * 8;

#define ABOFF(s_) (((s_) < KHS) ? (HSEG + (s_) * 32) : (XIN_OFF + ((s_) - KHS) * 32))

    if constexpr (IPBAR) {
        // single pair (NT <= 16): compute -> barrier -> overwrite input
        const int nt0 = ng, nt1 = ng + 8;
        const bool act0 = nt0 < NT;
        const bool act1 = nt1 < NT;
        f32x4 acc[2][2];
#pragma unroll
        for (int i = 0; i < 2; ++i)
#pragma unroll
            for (int m = 0; m < 2; ++m)
                acc[i][m] = (f32x4){0.f, 0.f, 0.f, 0.f};

        if (act0) {
            const u16* bp0 = wl + (size_t)nt0 * KS * 512;
            const u16* bp1 = wl + (size_t)nt1 * KS * 512;
#pragma unroll
            for (int s = 0; s < KS; ++s) {
                const int ab = ABOFF(s);
                const short8 a0 = *(const short8*)(arow0 + ab);
                const short8 a1 = *(const short8*)(arow1 + ab);
                const short8 w0 = *(const short8*)(bp0 + (size_t)s * 512);
                acc[0][0] = __builtin_amdgcn_mfma_f32_16x16x32_bf16(w0, a0, acc[0][0], 0, 0, 0);
                acc[0][1] = __builtin_amdgcn_mfma_f32_16x16x32_bf16(w0, a1, acc[0][1], 0, 0, 0);
                if (act1) {
                    const short8 w1 = *(const short8*)(bp1 + (size_t)s * 512);
                    acc[1][0] = __builtin_amdgcn_mfma_f32_16x16x32_bf16(w1, a0, acc[1][0], 0, 0, 0);
                    acc[1][1] = __builtin_amdgcn_mfma_f32_16x16x32_bf16(w1, a1, acc[1][1], 0, 0, 0);
                }
            }
        }
        __syncthreads();                   // all reads done before overwrite
        if (act0) store_nt<NACT, RELU>(acc[0], bias, s_act, nt0, mbase, lm, lq);
        if (act1) store_nt<NACT, RELU>(acc[1], bias, s_act, nt1, mbase, lm, lq);
    } else {
        // disjoint read/write regions (L0) or global out (L6): pair loop
        for (int g = 0;; ++g) {
            const int nt0 = ng + 16 * g;
            if (nt0 >= NT) break;
            const int nt1 = nt0 + 8;
            const bool act1 = nt1 < NT;
            f32x4 acc[2][2];
#pragma unroll
            for (int i = 0; i < 2; ++i)
#pragma unroll
                for (int m = 0; m < 2; ++m)
                    acc[i][m] = (f32x4){0.f, 0.f, 0.f, 0.f};

            const u16* bp0 = wl + (size_t)nt0 * KS * 512;
            const u16* bp1 = wl + (size_t)nt1 * KS * 512;
#pragma unroll
            for (int s = 0; s < KS; ++s) {
                const int ab = ABOFF(s);
                const short8 a0 = *(const short8*)(arow0 + ab);
                const short8 a1 = *(const short8*)(arow1 + ab);
                const short8 w0 = *(const short8*)(bp0 + (size_t)s * 512);
                acc[0][0] = __builtin_amdgcn_mfma_f32_16x16x32_bf16(w0, a0, acc[0][0], 0, 0, 0);
                acc[0][1] = __builtin_amdgcn_mfma_f32_16x16x32_bf16(w0, a1, acc[0][1], 0, 0, 0);
                if (act1) {
                    const short8 w1 = *(const short8*)(bp1 + (size_t)s * 512);
                    acc[1][0] = __builtin_amdgcn_mfma_f32_16x16x32_bf16(w1, a0, acc[1][0], 0, 0, 0);
                    acc[1][1] = __builtin_amdgcn_mfma_f32_16x16x32_bf16(w1, a1, acc[1][1], 0, 0, 0);
                }
            }

            if (GOUT) {
                // NT=1: only ng==0 reaches here; n=0,1 live in lq==0 regs 0,1
                if (lq == 0) {
                    const float b0 = bias[0], b1 = bias[1];
#pragma unroll
                    for (int m = 0; m < 2; ++m) {
                        float2 o;
                        o.x = acc[0][m][0] + b0;
                        o.y = acc[0][m][1] + b1;
                        *(float2*)(gout + (size_t)(p0 + (mbase + m) * 16 + lm) * 2) = o;
                    }
                }
            } else {
                store_nt<NACT, RELU>(acc[0], bias, s_act, nt0, mbase, lm, lq);
                if (act1)
                    store_nt<NACT, RELU>(acc[1], bias, s_act, nt1, mbase, lm, lq);
            }
        }
    }
#undef ABOFF
}

__global__ __launch_bounds__(NTH, 8)   // 8 waves/EU = 32 waves/CU = 2 blocks
void cont_decoder_mfma(MainParams p)
{
    extern __shared__ u16 s_act[];         // MPTS*SROW bf16 = 78848 B
    __shared__ int   s_x0[MPTS], s_y0[MPTS];
    __shared__ float s_wx[MPTS], s_wy[MPTS];

    const int tid  = threadIdx.x;
    const int wave = tid >> 6;
    const int lane = tid & 63;
    const int p0   = blockIdx.x * MPTS;
    const int b    = p0 >> 14;             // 16384 points per batch

    // ---- zero pad regions: xin[37..64) and H tail [592..608) ----
    for (int i = tid; i < MPTS * 43; i += NTH) {
        const int pt = i / 43, c = i % 43;
        const int col = (c < 27) ? (37 + c) : (592 + (c - 27));
        s_act[pt * SROW + col] = 0;
    }

    // ---- bilinear params + coord features ----
    if (tid < MPTS) {
        const int pt = p0 + tid;
        const float cx = p.coord[2 * pt];
        const float cy = p.coord[2 * pt + 1];
        const float gx = (cx + 1.0f) * 32.0f - 0.5f;   // align_corners=False
        const float gy = (cy + 1.0f) * 32.0f - 0.5f;
        const float fx0 = floorf(gx), fy0 = floorf(gy);
        s_x0[tid] = (int)fx0;
        s_y0[tid] = (int)fy0;
        s_wx[tid] = gx - fx0;
        s_wy[tid] = gy - fy0;
        s_act[tid * SROW + 32] = f2bf(cx);
        s_act[tid * SROW + 33] = f2bf(cy);
    }
    __syncthreads();

    // ---- sample 35 channels/point (ref swaps spatial axes: val = g[b,c,x,y]) ----
    for (int idx = tid; idx < MPTS * 35; idx += NTH) {
        const int t = idx / 35;
        const int c = idx % 35;
        const float* base;
        int col;
        if (c < 32)      { base = p.ctx + (size_t)(b * 32 + c) * 4096;       col = c; }
        else if (c < 34) { base = p.lr  + (size_t)(b * 2 + (c - 32)) * 4096; col = 34 + (c - 32); }
        else             { base = p.eps + (size_t)b * 4096;                   col = 36; }

        const int   x0 = s_x0[t], y0 = s_y0[t];
        const float wx = s_wx[t], wy = s_wy[t];
        const int x1 = x0 + 1, y1 = y0 + 1;
        const bool xv0 = (x0 >= 0) & (x0 < 64);
        const bool xv1 = (x1 >= 0) & (x1 < 64);
        const bool yv0 = (y0 >= 0) & (y0 < 64);
        const bool yv1 = (y1 >= 0) & (y1 < 64);
        const int xc0 = min(max(x0, 0), 63), xc1 = min(max(x1, 0), 63);
        const int yc0 = min(max(y0, 0), 63), yc1 = min(max(y1, 0), 63);

        const float w00 = (1.0f - wx) * (1.0f - wy) * ((xv0 && yv0) ? 1.0f : 0.0f);
        const float w10 = wx * (1.0f - wy)          * ((xv1 && yv0) ? 1.0f : 0.0f);
        const float w01 = (1.0f - wx) * wy          * ((xv0 && yv1) ? 1.0f : 0.0f);
        const float w11 = wx * wy                   * ((xv1 && yv1) ? 1.0f : 0.0f);

        const float val = w00 * base[xc0 * 64 + yc0]
                        + w10 * base[xc1 * 64 + yc0]
                        + w01 * base[xc0 * 64 + yc1]
                        + w11 * base[xc1 * 64 + yc1];
        s_act[t * SROW + col] = f2bf(val);
    }
    __syncthreads();

    // ---- MLP:  xin(37p64) ->W0-> H(516p544) ->W1-> H(256) ->W2-> H(128)
    //            ->W3-> H(64) ->W4-> H(32) ->W5-> H(16) ->W6-> out(2)
    //     KHP  NT  NACT LBASE    XIN    RELU   GOUT   IPBAR
    mlayer<  0, 33, 516, 0,      true,  true,  false, false>(p.wpack, p.Bb[0], s_act, nullptr, p0, wave, lane);
    __syncthreads();
    mlayer<544, 16, 256, 33792,  true,  true,  false, true >(p.wpack, p.Bb[1], s_act, nullptr, p0, wave, lane);
    __syncthreads();
    mlayer<256,  8, 128, 189440, true,  true,  false, true >(p.wpack, p.Bb[2], s_act, nullptr, p0, wave, lane);
    __syncthreads();
    mlayer<128,  4,  64, 230400, true,  true,  false, true >(p.wpack, p.Bb[3], s_act, nullptr, p0, wave, lane);
    __syncthreads();
    mlayer< 64,  2,  32, 242688, true,  true,  false, true >(p.wpack, p.Bb[4], s_act, nullptr, p0, wave, lane);
    __syncthreads();
    mlayer< 32,  1,  16, 246784, true,  true,  false, true >(p.wpack, p.Bb[5], s_act, nullptr, p0, wave, lane);
    __syncthreads();
    mlayer< 32,  1,   2, 248320, false, false, true,  false>(p.wpack, p.Bb[6], s_act, p.out,   p0, wave, lane);
}

extern "C" void kernel_launch(void* const* d_in, const int* in_sizes, int n_in,
                              void* d_out, int out_size, void* d_ws, size_t ws_size,
                              hipStream_t stream)
{
    WPtrs wp;
    for (int l = 0; l < 7; ++l) wp.W[l] = (const float*)d_in[4 + 2 * l];

    MainParams p;
    p.lr    = (const float*)d_in[0];
    p.ctx   = (const float*)d_in[1];
    p.eps   = (const float*)d_in[2];
    p.coord = (const float*)d_in[3];
    for (int l = 0; l < 7; ++l) p.Bb[l] = (const float*)d_in[5 + 2 * l];
    p.wpack = (const u16*)d_ws;
    p.out   = (float*)d_out;

    // Opt in to large dynamic LDS (idempotent; not a stream op, capture-safe).
    hipFuncSetAttribute((const void*)cont_decoder_mfma,
                        hipFuncAttributeMaxDynamicSharedMemorySize, LDSBYTES);

    hipLaunchKernelGGL(pack_weights, dim3(122), dim3(256), 0, stream, wp, (u16*)d_ws);
    hipLaunchKernelGGL(cont_decoder_mfma, dim3(GRIDX), dim3(NTH), LDSBYTES, stream, p);
}